// Round 15
// baseline (363.762 us; speedup 1.0000x reference)
//
#include <hip/hip_runtime.h>

typedef unsigned char uchar;
typedef unsigned short ushort;
typedef unsigned int uint;

constexpr int NN = 50000;
constexpr int NE = 1600000;
constexpr int NG = 1000;
constexpr int NB2 = 196;             // coarse buckets of 256 dst nodes
constexpr int TILE = 4096;           // bin_kernel tile (edges per block)
constexpr int NTILE = (NE + TILE - 1) / TILE;   // 391
constexpr int SPAN_CAP = 9216;       // bucket span cap (mean 8163, +11 sigma)
constexpr int MSTRIDE = 72;          // bf16 LDS row stride (64 + 8 pad)

// workspace layout in 4-byte units
constexpr int OFF_BCNT  = 0;          // int[256]    (zeroed)
constexpr int OFF_SUMS  = 256;        // f32[64000]  (zeroed)
constexpr int OFF_CNT   = 64256;      // f32[1024]   (zeroed)
constexpr int ZERO_UNITS= 65280;
constexpr int OFF_BBASE = 65280;      // int[256]
constexpr int OFF_BCUR  = 65536;      // int[256]
constexpr int OFF_OFFS  = 65792;      // int[50176]
constexpr int OFF_P0    = 116224;     // uint[NE]  src | dstloc<<16  (src < 65536 since NN=50000)
constexpr int OFF_P1    = 1716224;    // uint[NE]  ea01 bf16x2
constexpr int OFF_P2    = 3316224;    // uint[NE]  ea23 bf16x2
constexpr int OFF_A1    = 4916224;    // f32[NN*8] aggr1 (16B-aligned)
constexpr int OFF_H1    = 5316224;    // uint[NN*32] packed bf16 h1
constexpr int OFF_Z     = 6916224;    // uint[NN*32] packed bf16 z (16B-aligned)
// end = 8,516,224 units = 34.1 MB

typedef __attribute__((ext_vector_type(8))) short short8;
typedef __attribute__((ext_vector_type(4))) float float4v;

__device__ __forceinline__ uint f2bf(float f) {
    uint u = __float_as_uint(f);
    return (u + 0x7fffu + ((u >> 16) & 1u)) >> 16;
}
__device__ __forceinline__ float bf2f_lo(uint p) { return __uint_as_float(p << 16); }
__device__ __forceinline__ float bf2f_hi(uint p) { return __uint_as_float(p & 0xffff0000u); }

// ---------- coarse-bucket histogram ----------
__global__ __launch_bounds__(256) void bhist_kernel(const int* __restrict__ eidx,
                                                    int* __restrict__ bcnt) {
    __shared__ int lh[NB2];
    for (int i = threadIdx.x; i < NB2; i += 256) lh[i] = 0;
    __syncthreads();
    int tid = blockIdx.x * 256 + threadIdx.x;
    int stride = gridDim.x * 256;
    for (int e = tid; e < NE; e += stride) atomicAdd(&lh[eidx[NE + e] >> 8], 1);
    __syncthreads();
    for (int i = threadIdx.x; i < NB2; i += 256) if (lh[i]) atomicAdd(&bcnt[i], lh[i]);
}

// ---------- bucket scan ----------
__global__ __launch_bounds__(256) void bscan_kernel(const int* __restrict__ bcnt,
                                                    int* __restrict__ bbase,
                                                    int* __restrict__ bcur) {
    __shared__ int s[256];
    int t = threadIdx.x;
    int v = (t < NB2) ? bcnt[t] : 0;
    s[t] = v; __syncthreads();
    for (int o = 1; o < 256; o <<= 1) {
        int u = (t >= o) ? s[t - o] : 0;
        __syncthreads();
        s[t] += u;
        __syncthreads();
    }
    bbase[t] = s[t] - v;
    bcur[t] = s[t] - v;
}

// ---------- phase 1: bin edges into coarse buckets ----------
__global__ __launch_bounds__(256) void bin_kernel(const int* __restrict__ eidx,
                                                  const float4* __restrict__ ea,
                                                  int* __restrict__ bcur,
                                                  uint* __restrict__ p0,
                                                  uint* __restrict__ p1,
                                                  uint* __restrict__ p2) {
    __shared__ uint s0[TILE], s1[TILE], s2[TILE];
    __shared__ int hcnt[NB2], hoff[NB2 + 1], hcur[NB2], gbase[NB2];
    const int t = threadIdx.x;
    const int e0 = blockIdx.x * TILE;
    const int cnt = (NE - e0 < TILE) ? (NE - e0) : TILE;
    for (int i = t; i < NB2; i += 256) hcnt[i] = 0;
    __syncthreads();
    int dsts[16];
    #pragma unroll
    for (int k = 0; k < 16; ++k) {
        int i = t + k * 256;
        int d = (i < cnt) ? eidx[NE + e0 + i] : -1;
        dsts[k] = d;
        if (d >= 0) atomicAdd(&hcnt[d >> 8], 1);
    }
    __syncthreads();
    if (t == 0) {
        int a = 0;
        for (int b = 0; b < NB2; ++b) { hoff[b] = a; a += hcnt[b]; }
        hoff[NB2] = a;
    }
    __syncthreads();
    if (t < NB2) { hcur[t] = hoff[t]; gbase[t] = atomicAdd(&bcur[t], hcnt[t]); }
    __syncthreads();
    #pragma unroll
    for (int k = 0; k < 16; ++k) {
        int d = dsts[k];
        if (d < 0) continue;
        int i = t + k * 256;
        int e = e0 + i;
        int src = eidx[e];
        float4 a = ea[e];
        int lp = atomicAdd(&hcur[d >> 8], 1);
        s0[lp] = (uint)src | ((uint)(d & 255) << 16);
        s1[lp] = f2bf(a.x) | (f2bf(a.y) << 16);
        s2[lp] = f2bf(a.z) | (f2bf(a.w) << 16);
    }
    __syncthreads();
    for (int i = t; i < cnt; i += 256) {
        int lo = 0, hi = NB2 - 1;
        while (lo < hi) { int mid = (lo + hi + 1) >> 1; if (hoff[mid] <= i) lo = mid; else hi = mid - 1; }
        int gp = gbase[lo] + (i - hoff[lo]);
        p0[gp] = s0[i]; p1[gp] = s1[i]; p2[gp] = s2[i];
    }
}

// ---------- phase 2: per-bucket degrees + offs + permute + FUSED layer-1 edge pass ----------
__global__ __launch_bounds__(256) void build_kernel(const int* __restrict__ bbase,
                                                    const int* __restrict__ bcnt,
                                                    const float* __restrict__ x,
                                                    const float* __restrict__ We1,
                                                    const float* __restrict__ be1,
                                                    int* __restrict__ offs,
                                                    uint* __restrict__ p0,
                                                    uint* __restrict__ p1,
                                                    uint* __restrict__ p2,
                                                    float* __restrict__ aggr1) {
    __shared__ uint s0[SPAN_CAP], s1[SPAN_CAP], s2[SPAN_CAP];
    __shared__ int ldeg[256], lcur[256], sscan[256];
    __shared__ float laggr[256][8];
    __shared__ float sWe[32];     // [k_in 0..3][d_out 0..7], col 7 zeroed
    __shared__ float sbe[8];
    const int t = threadIdx.x;
    const int b = blockIdx.x;
    const int nlo = b << 8;
    const int base = bbase[b];
    int span = bcnt[b];
    if (span > SPAN_CAP) span = SPAN_CAP;
    ldeg[t] = 0;
    if (t < 32) { int k = t >> 3, dd = t & 7; sWe[t] = (dd < 7) ? We1[k * 7 + dd] : 0.f; }
    if (t < 8)  sbe[t] = (t < 7) ? be1[t] : 0.f;
    #pragma unroll
    for (int d = 0; d < 8; ++d) laggr[t][d] = 0.f;
    __syncthreads();
    for (int i = t; i < span; i += 256)
        atomicAdd(&ldeg[(p0[base + i] >> 16) & 0xFFu], 1);
    __syncthreads();
    int v = ldeg[t];
    sscan[t] = v; __syncthreads();
    for (int o = 1; o < 256; o <<= 1) {
        int u = (t >= o) ? sscan[t - o] : 0;
        __syncthreads();
        sscan[t] += u;
        __syncthreads();
    }
    int exc = sscan[t] - v;
    lcur[t] = exc;
    int gi = nlo + t;
    if (gi < NN) offs[gi] = base + exc;
    else if (gi < 50176) offs[gi] = NE;
    __syncthreads();
    for (int i = t; i < span; i += 256) {
        uint r0 = p0[base + i], r1 = p1[base + i], r2 = p2[base + i];
        int pos = atomicAdd(&lcur[(r0 >> 16) & 0xFFu], 1);
        s0[pos] = r0; s1[pos] = r1; s2[pos] = r2;
    }
    __syncthreads();
    // writeback CSR-ordered records + fused layer-1 message accumulation (LDS atomics)
    for (int i = t; i < span; i += 256) {
        uint r0 = s0[i], r1 = s1[i], r2 = s2[i];
        p0[base + i] = r0; p1[base + i] = r1; p2[base + i] = r2;
        int src = (int)(r0 & 0xFFFFu);
        int dl  = (int)((r0 >> 16) & 0xFFu);
        float e0 = bf2f_lo(r1), e1 = bf2f_hi(r1);
        float e2 = bf2f_lo(r2), e3 = bf2f_hi(r2);
        const float* xs = x + (size_t)src * 7;
        #pragma unroll
        for (int d = 0; d < 7; ++d) {
            float m = sbe[d] + e0 * sWe[d] + e1 * sWe[8 + d]
                    + e2 * sWe[16 + d] + e3 * sWe[24 + d] + xs[d];
            atomicAdd(&laggr[dl][d], fmaxf(m, 0.f));       // ds_add_f32
        }
    }
    __syncthreads();
    if (nlo + t < NN) {
        float4 a0 = make_float4(laggr[t][0], laggr[t][1], laggr[t][2], laggr[t][3]);
        float4 a1 = make_float4(laggr[t][4], laggr[t][5], laggr[t][6], 0.f);
        *(float4*)(aggr1 + (size_t)(nlo + t) * 8)     = a0;
        *(float4*)(aggr1 + (size_t)(nlo + t) * 8 + 4) = a1;
    }
}

// ---------- node-1 MLP via MFMA (z = x + aggr1 formed in registers) ----------
__global__ __launch_bounds__(256) void node1_kernel(
    const float* __restrict__ x, const float* __restrict__ aggr1,
    const float* __restrict__ W1a, const float* __restrict__ b1a,
    const float* __restrict__ W1b, const float* __restrict__ b1b,
    uint* __restrict__ h1u)
{
    __shared__ __align__(16) ushort sT[64 * MSTRIDE];
    __shared__ __align__(16) ushort sO[64 * 64];
    const int t = threadIdx.x;
    const int w = t >> 6, lane = t & 63;
    const int qm = lane & 15, quad = lane >> 4;
    const int n0 = blockIdx.x * 64;
    const int node = n0 + w * 16 + qm;

    short8 wa1n[4];
    #pragma unroll
    for (int nt = 0; nt < 4; ++nt) {
        short8 v = (short8)0;
        if (quad == 0) {
            #pragma unroll
            for (int j = 0; j < 7; ++j)
                v[j] = (short)f2bf(W1a[j * 64 + nt * 16 + qm]);
        }
        wa1n[nt] = v;
    }
    short8 wb1[2][4];
    #pragma unroll
    for (int s = 0; s < 2; ++s)
        #pragma unroll
        for (int nt = 0; nt < 4; ++nt) {
            short8 v;
            #pragma unroll
            for (int j = 0; j < 8; ++j)
                v[j] = (short)f2bf(W1b[(s * 32 + quad * 8 + j) * 64 + nt * 16 + qm]);
            wb1[s][nt] = v;
        }
    float ba[4], bb[4];
    #pragma unroll
    for (int nt = 0; nt < 4; ++nt) { ba[nt] = b1a[nt * 16 + qm]; bb[nt] = b1b[nt * 16 + qm]; }

    short8 af1 = (short8)0;
    if (quad == 0 && node < NN) {
        const float* xs = x + (size_t)node * 7;
        const float4 a0 = *(const float4*)(aggr1 + (size_t)node * 8);
        const float4 a1 = *(const float4*)(aggr1 + (size_t)node * 8 + 4);
        af1[0] = (short)f2bf(xs[0] + a0.x); af1[1] = (short)f2bf(xs[1] + a0.y);
        af1[2] = (short)f2bf(xs[2] + a0.z); af1[3] = (short)f2bf(xs[3] + a0.w);
        af1[4] = (short)f2bf(xs[4] + a1.x); af1[5] = (short)f2bf(xs[5] + a1.y);
        af1[6] = (short)f2bf(xs[6] + a1.z); af1[7] = 0;
    }
    float4v acc[4];
    #pragma unroll
    for (int nt = 0; nt < 4; ++nt) {
        acc[nt] = (float4v){0.f, 0.f, 0.f, 0.f};
        acc[nt] = __builtin_amdgcn_mfma_f32_16x16x32_bf16(af1, wa1n[nt], acc[nt], 0, 0, 0);
    }
    #pragma unroll
    for (int nt = 0; nt < 4; ++nt)
        #pragma unroll
        for (int r = 0; r < 4; ++r)
            sT[(w * 16 + quad * 4 + r) * MSTRIDE + nt * 16 + qm] =
                (ushort)f2bf(fmaxf(acc[nt][r] + ba[nt], 0.f));
    __syncthreads();

    #pragma unroll
    for (int nt = 0; nt < 4; ++nt) acc[nt] = (float4v){0.f, 0.f, 0.f, 0.f};
    #pragma unroll
    for (int s = 0; s < 2; ++s) {
        short8 af = *(const short8*)&sT[(w * 16 + qm) * MSTRIDE + s * 32 + quad * 8];
        #pragma unroll
        for (int nt = 0; nt < 4; ++nt)
            acc[nt] = __builtin_amdgcn_mfma_f32_16x16x32_bf16(af, wb1[s][nt], acc[nt], 0, 0, 0);
    }
    #pragma unroll
    for (int nt = 0; nt < 4; ++nt)
        #pragma unroll
        for (int r = 0; r < 4; ++r)
            sO[(w * 16 + quad * 4 + r) * 64 + nt * 16 + qm] =
                (ushort)f2bf(fmaxf(acc[nt][r] + bb[nt], 0.f));
    __syncthreads();
    for (int i = t; i < 64 * 32; i += 256) {
        int nd = i >> 5;
        if (n0 + nd < NN) h1u[(size_t)(n0 + nd) * 32 + (i & 31)] = ((const uint*)sO)[i];
    }
}

// ---------- Layer 2 aggregation: R12-proven form (2 dims/lane, masked 16-edge batches) ----------
__global__ __launch_bounds__(256) void aggr2_kernel(
    const uint* __restrict__ h1u,
    const uint* __restrict__ p0, const uint* __restrict__ p1, const uint* __restrict__ p2,
    const int* __restrict__ offs,
    const float* __restrict__ We2, const float* __restrict__ be2,
    uint* __restrict__ zb)
{
    __shared__ float sWe[256];
    __shared__ float sbe[64];
    int tid = threadIdx.x;
    sWe[tid] = We2[tid];
    if (tid < 64) sbe[tid] = be2[tid];
    __syncthreads();
    const int w = tid >> 6, lane = tid & 63;
    const int l = lane & 31;
    const int half8 = (lane >> 5) << 3;
    const int n = blockIdx.x * 4 + w;
    const int off = offs[n];
    const int deg = offs[n + 1] - off;
    const float w0x = sWe[2 * l],       w0y = sWe[2 * l + 1];
    const float w1x = sWe[64 + 2 * l],  w1y = sWe[64 + 2 * l + 1];
    const float w2x = sWe[128 + 2 * l], w2y = sWe[128 + 2 * l + 1];
    const float w3x = sWe[192 + 2 * l], w3y = sWe[192 + 2 * l + 1];
    const float bbx = sbe[2 * l],       bby = sbe[2 * l + 1];

    float accx = 0.f, accy = 0.f;
    for (int jb = 0; jb < deg; jb += 16) {
        int m = deg - jb;
        int ll = (lane < 16) ? ((lane < m) ? lane : 0) : 0;
        int idx = off + jb + ll;
        int sx = (int)(p0[idx] & 0xFFFFu);
        uint e01 = p1[idx];
        uint e23 = p2[idx];
        uint g[8];
        #pragma unroll
        for (int k = 0; k < 8; ++k) {
            int mk = k + half8;
            int sk = __shfl(sx, (mk < m) ? mk : 0);
            g[k] = h1u[(size_t)sk * 32 + l];
        }
        #pragma unroll
        for (int k = 0; k < 8; ++k) {
            int mk = k + half8;
            int sl = (mk < m) ? mk : 0;
            uint py = (uint)__shfl((int)e01, sl);
            uint pz = (uint)__shfl((int)e23, sl);
            float e0 = bf2f_lo(py), e1 = bf2f_hi(py);
            float e2 = bf2f_lo(pz), e3 = bf2f_hi(pz);
            float bx = bbx + e0 * w0x + e1 * w1x + e2 * w2x + e3 * w3x;
            float by = bby + e0 * w0y + e1 * w1y + e2 * w2y + e3 * w3y;
            float tx = fmaxf(bf2f_lo(g[k]) + bx, 0.f);
            float ty = fmaxf(bf2f_hi(g[k]) + by, 0.f);
            if (mk < m) { accx += tx; accy += ty; }
        }
    }
    accx += __shfl_xor(accx, 32);
    accy += __shfl_xor(accy, 32);
    if (lane < 32) {
        uint sw = h1u[(size_t)n * 32 + l];
        float zx = bf2f_lo(sw) + accx;
        float zy = bf2f_hi(sw) + accy;
        zb[(size_t)n * 32 + l] = f2bf(zx) | (f2bf(zy) << 16);
    }
}

// ---------- Layer 2 MLP via MFMA + segmented-reduction pooling ----------
__global__ __launch_bounds__(256) void mlp2_kernel(
    const uint* __restrict__ zb,
    const float* __restrict__ W2a, const float* __restrict__ b2a,
    const float* __restrict__ W2b, const float* __restrict__ b2b,
    const int* __restrict__ batch,
    float* __restrict__ sums, float* __restrict__ cnt)
{
    __shared__ __align__(16) ushort sT[64 * MSTRIDE];
    __shared__ float sH[64 * 64];
    __shared__ int sB[64];
    __shared__ float pbuf[4][64];
    __shared__ int pcnt[4];
    const int t = threadIdx.x;
    const int w = t >> 6, lane = t & 63;
    const int qm = lane & 15, quad = lane >> 4;
    const int n0 = blockIdx.x * 64;
    const int node = n0 + w * 16 + qm;
    const int nv = (NN - n0 < 64) ? (NN - n0) : 64;

    if (t < 64) sB[t] = (n0 + t < NN) ? batch[n0 + t] : -2;

    short8 wa[2][4], wb[2][4];
    #pragma unroll
    for (int s = 0; s < 2; ++s)
        #pragma unroll
        for (int nt = 0; nt < 4; ++nt) {
            short8 va, vb;
            #pragma unroll
            for (int j = 0; j < 8; ++j) {
                int k = s * 32 + quad * 8 + j, n = nt * 16 + qm;
                va[j] = (short)f2bf(W2a[k * 64 + n]);
                vb[j] = (short)f2bf(W2b[k * 64 + n]);
            }
            wa[s][nt] = va; wb[s][nt] = vb;
        }
    float ba[4], bb[4];
    #pragma unroll
    for (int nt = 0; nt < 4; ++nt) { ba[nt] = b2a[nt * 16 + qm]; bb[nt] = b2b[nt * 16 + qm]; }

    float4v acc[4];
    #pragma unroll
    for (int nt = 0; nt < 4; ++nt) acc[nt] = (float4v){0.f, 0.f, 0.f, 0.f};
    #pragma unroll
    for (int s = 0; s < 2; ++s) {
        uint4 zw = (node < NN) ? *(const uint4*)&zb[(size_t)node * 32 + s * 16 + quad * 4]
                               : make_uint4(0, 0, 0, 0);
        short8 af;
        *(uint4*)&af = zw;
        #pragma unroll
        for (int nt = 0; nt < 4; ++nt)
            acc[nt] = __builtin_amdgcn_mfma_f32_16x16x32_bf16(af, wa[s][nt], acc[nt], 0, 0, 0);
    }
    #pragma unroll
    for (int nt = 0; nt < 4; ++nt)
        #pragma unroll
        for (int r = 0; r < 4; ++r)
            sT[(w * 16 + quad * 4 + r) * MSTRIDE + nt * 16 + qm] =
                (ushort)f2bf(fmaxf(acc[nt][r] + ba[nt], 0.f));
    __syncthreads();

    #pragma unroll
    for (int nt = 0; nt < 4; ++nt) acc[nt] = (float4v){0.f, 0.f, 0.f, 0.f};
    #pragma unroll
    for (int s = 0; s < 2; ++s) {
        short8 af = *(const short8*)&sT[(w * 16 + qm) * MSTRIDE + s * 32 + quad * 8];
        #pragma unroll
        for (int nt = 0; nt < 4; ++nt)
            acc[nt] = __builtin_amdgcn_mfma_f32_16x16x32_bf16(af, wb[s][nt], acc[nt], 0, 0, 0);
    }
    #pragma unroll
    for (int nt = 0; nt < 4; ++nt)
        #pragma unroll
        for (int r = 0; r < 4; ++r)
            sH[(w * 16 + quad * 4 + r) * 64 + nt * 16 + qm] = fmaxf(acc[nt][r] + bb[nt], 0.f);
    __syncthreads();

    const int glo = sB[0];
    const int ghi = sB[nv - 1];
    const int c = t >> 6, d = t & 63;
    for (int g = glo; g <= ghi; ++g) {
        float p = 0.f;
        int lc = 0;
        #pragma unroll 4
        for (int i = 0; i < 16; ++i) {
            int nd = c * 16 + i;
            if (sB[nd] == g) { p += sH[nd * 64 + d]; ++lc; }
        }
        pbuf[c][d] = p;
        if (d == 0) pcnt[c] = lc;
        __syncthreads();
        int tc = pcnt[0] + pcnt[1] + pcnt[2] + pcnt[3];
        if (tc > 0) {
            if (c == 0) {
                float tot = pbuf[0][d] + pbuf[1][d] + pbuf[2][d] + pbuf[3][d];
                atomicAdd(&sums[(size_t)g * 64 + d], tot);
            }
            if (t == 0) atomicAdd(&cnt[g], (float)tc);
        }
        __syncthreads();
    }
}

// ---------- FC ----------
__global__ __launch_bounds__(256) void fc_kernel(
    const float* __restrict__ sums, const float* __restrict__ cnt,
    const float* __restrict__ Wfc, const float* __restrict__ bfc,
    float* __restrict__ out)
{
    int gid = blockIdx.x * blockDim.x + threadIdx.x;
    if (gid >= NG * 12) return;
    int g = gid / 12, jj = gid - g * 12;
    float inv = 1.f / fmaxf(cnt[g], 1.f);
    float acc = bfc[jj];
    #pragma unroll 8
    for (int k = 0; k < 64; ++k) acc += sums[(size_t)g * 64 + k] * inv * Wfc[k * 12 + jj];
    out[gid] = acc;
}

extern "C" void kernel_launch(void* const* d_in, const int* in_sizes, int n_in,
                              void* d_out, int out_size, void* d_ws, size_t ws_size,
                              hipStream_t stream)
{
    (void)in_sizes; (void)n_in; (void)out_size; (void)ws_size;
    const float*  x    = (const float*)d_in[0];
    const float4* ea   = (const float4*)d_in[1];
    const int*    eidx = (const int*)d_in[2];
    const int*    batch= (const int*)d_in[3];
    const float*  We1  = (const float*)d_in[4];
    const float*  be1  = (const float*)d_in[5];
    const float*  W1a  = (const float*)d_in[6];
    const float*  b1a  = (const float*)d_in[7];
    const float*  W1b  = (const float*)d_in[8];
    const float*  b1b  = (const float*)d_in[9];
    const float*  We2  = (const float*)d_in[10];
    const float*  be2  = (const float*)d_in[11];
    const float*  W2a  = (const float*)d_in[12];
    const float*  b2a  = (const float*)d_in[13];
    const float*  W2b  = (const float*)d_in[14];
    const float*  b2b  = (const float*)d_in[15];
    const float*  Wfc  = (const float*)d_in[16];
    const float*  bfc  = (const float*)d_in[17];
    float* out = (float*)d_out;
    float* ws  = (float*)d_ws;

    int*   bcnt  = (int*)(ws + OFF_BCNT);
    float* sums  = ws + OFF_SUMS;
    float* cnt   = ws + OFF_CNT;
    int*   bbase = (int*)(ws + OFF_BBASE);
    int*   bcur  = (int*)(ws + OFF_BCUR);
    int*   offs  = (int*)(ws + OFF_OFFS);
    uint*  p0    = (uint*)(ws + OFF_P0);
    uint*  p1    = (uint*)(ws + OFF_P1);
    uint*  p2    = (uint*)(ws + OFF_P2);
    float* aggr1 = ws + OFF_A1;
    uint*  h1u   = (uint*)(ws + OFF_H1);
    uint*  zb    = (uint*)(ws + OFF_Z);

    hipMemsetAsync(d_ws, 0, (size_t)ZERO_UNITS * 4, stream);

    bhist_kernel<<<256, 256, 0, stream>>>(eidx, bcnt);
    bscan_kernel<<<1, 256, 0, stream>>>(bcnt, bbase, bcur);
    bin_kernel  <<<NTILE, 256, 0, stream>>>(eidx, ea, bcur, p0, p1, p2);
    build_kernel<<<NB2, 256, 0, stream>>>(bbase, bcnt, x, We1, be1, offs, p0, p1, p2, aggr1);
    node1_kernel<<<(NN + 63) / 64, 256, 0, stream>>>(x, aggr1, W1a, b1a, W1b, b1b, h1u);
    aggr2_kernel<<<12500, 256, 0, stream>>>(h1u, p0, p1, p2, offs, We2, be2, zb);
    mlp2_kernel <<<(NN + 63) / 64, 256, 0, stream>>>(zb, W2a, b2a, W2b, b2b, batch, sums, cnt);
    fc_kernel   <<<(NG * 12 + 255) / 256, 256, 0, stream>>>(sums, cnt, Wfc, bfc, out);
}

// Round 16
// 283.367 us; speedup vs baseline: 1.2837x; 1.2837x over previous
//
#include <hip/hip_runtime.h>

typedef unsigned char uchar;
typedef unsigned short ushort;
typedef unsigned int uint;

constexpr int NN = 50000;
constexpr int NE = 1600000;
constexpr int NG = 1000;
constexpr int NB2 = 196;             // coarse buckets of 256 dst nodes
constexpr int TILE = 4096;           // bin_kernel tile (edges per block)
constexpr int NTILE = (NE + TILE - 1) / TILE;   // 391
constexpr int SPAN_CAP = 9216;       // bucket span cap (mean 8163, +11 sigma)
constexpr int MSTRIDE = 72;          // bf16 LDS row stride (64 + 8 pad)

// workspace layout in 4-byte units (R12 layout)
constexpr int OFF_BCNT  = 0;          // int[256]    (zeroed)
constexpr int OFF_SUMS  = 256;        // f32[64000]  (zeroed)
constexpr int OFF_CNT   = 64256;      // f32[1024]   (zeroed)
constexpr int ZERO_UNITS= 65280;
constexpr int OFF_BBASE = 65280;      // int[256]
constexpr int OFF_BCUR  = 65536;      // int[256]
constexpr int OFF_OFFS  = 65792;      // int[50176]
constexpr int OFF_P0    = 116224;     // uint[NE]  src | dstloc<<16 | bucket<<24
constexpr int OFF_P1    = 1716224;    // uint[NE]  ea01 bf16x2
constexpr int OFF_P2    = 3316224;    // uint[NE]  ea23 bf16x2
constexpr int OFF_Z1    = 4916224;    // f32[NN*8]  (16B-aligned)
constexpr int OFF_H1    = 5316224;    // uint[NN*32] packed bf16 h1
constexpr int OFF_Z     = 6916224;    // uint[NN*32] packed bf16 z (16B-aligned)
// end = 8,516,224 units = 34.1 MB

typedef __attribute__((ext_vector_type(8))) short short8;
typedef __attribute__((ext_vector_type(4))) float float4v;
typedef __attribute__((ext_vector_type(2))) float float2v;

__device__ __forceinline__ uint f2bf(float f) {
    uint u = __float_as_uint(f);
    return (u + 0x7fffu + ((u >> 16) & 1u)) >> 16;
}
__device__ __forceinline__ float bf2f_lo(uint p) { return __uint_as_float(p << 16); }
__device__ __forceinline__ float bf2f_hi(uint p) { return __uint_as_float(p & 0xffff0000u); }

// ---------- coarse-bucket histogram ----------
__global__ __launch_bounds__(256) void bhist_kernel(const int* __restrict__ eidx,
                                                    int* __restrict__ bcnt) {
    __shared__ int lh[NB2];
    for (int i = threadIdx.x; i < NB2; i += 256) lh[i] = 0;
    __syncthreads();
    int tid = blockIdx.x * 256 + threadIdx.x;
    int stride = gridDim.x * 256;
    for (int e = tid; e < NE; e += stride) atomicAdd(&lh[eidx[NE + e] >> 8], 1);
    __syncthreads();
    for (int i = threadIdx.x; i < NB2; i += 256) if (lh[i]) atomicAdd(&bcnt[i], lh[i]);
}

// ---------- bucket scan ----------
__global__ __launch_bounds__(256) void bscan_kernel(const int* __restrict__ bcnt,
                                                    int* __restrict__ bbase,
                                                    int* __restrict__ bcur) {
    __shared__ int s[256];
    int t = threadIdx.x;
    int v = (t < NB2) ? bcnt[t] : 0;
    s[t] = v; __syncthreads();
    for (int o = 1; o < 256; o <<= 1) {
        int u = (t >= o) ? s[t - o] : 0;
        __syncthreads();
        s[t] += u;
        __syncthreads();
    }
    bbase[t] = s[t] - v;
    bcur[t] = s[t] - v;
}

// ---------- phase 1: bin edges into coarse buckets ----------
__global__ __launch_bounds__(256) void bin_kernel(const int* __restrict__ eidx,
                                                  const float4* __restrict__ ea,
                                                  int* __restrict__ bcur,
                                                  uint* __restrict__ p0,
                                                  uint* __restrict__ p1,
                                                  uint* __restrict__ p2) {
    __shared__ uint s0[TILE], s1[TILE], s2[TILE];
    __shared__ int hcnt[NB2], hoff[NB2 + 1], hcur[NB2], gbase[NB2];
    const int t = threadIdx.x;
    const int e0 = blockIdx.x * TILE;
    const int cnt = (NE - e0 < TILE) ? (NE - e0) : TILE;
    for (int i = t; i < NB2; i += 256) hcnt[i] = 0;
    __syncthreads();
    int dsts[16];
    #pragma unroll
    for (int k = 0; k < 16; ++k) {
        int i = t + k * 256;
        int d = (i < cnt) ? eidx[NE + e0 + i] : -1;
        dsts[k] = d;
        if (d >= 0) atomicAdd(&hcnt[d >> 8], 1);
    }
    __syncthreads();
    if (t == 0) {
        int a = 0;
        for (int b = 0; b < NB2; ++b) { hoff[b] = a; a += hcnt[b]; }
        hoff[NB2] = a;
    }
    __syncthreads();
    if (t < NB2) { hcur[t] = hoff[t]; gbase[t] = atomicAdd(&bcur[t], hcnt[t]); }
    __syncthreads();
    #pragma unroll
    for (int k = 0; k < 16; ++k) {
        int d = dsts[k];
        if (d < 0) continue;
        int i = t + k * 256;
        int e = e0 + i;
        int src = eidx[e];
        float4 a = ea[e];
        int bkt = d >> 8;
        int lp = atomicAdd(&hcur[bkt], 1);
        s0[lp] = (uint)src | ((uint)(d & 255) << 16) | ((uint)bkt << 24);  // bucket in spare byte
        s1[lp] = f2bf(a.x) | (f2bf(a.y) << 16);
        s2[lp] = f2bf(a.z) | (f2bf(a.w) << 16);
    }
    __syncthreads();
    for (int i = t; i < cnt; i += 256) {            // no binary search: bucket id from s0 top byte
        uint r0 = s0[i];
        int bkt = (int)(r0 >> 24);
        int gp = gbase[bkt] + (i - hoff[bkt]);
        p0[gp] = r0; p1[gp] = s1[i]; p2[gp] = s2[i];
    }
}

// ---------- phase 2: per-bucket degrees + offs + in-place permute (R12-proven) ----------
__global__ __launch_bounds__(256) void build_kernel(const int* __restrict__ bbase,
                                                    const int* __restrict__ bcnt,
                                                    int* __restrict__ offs,
                                                    uint* __restrict__ p0,
                                                    uint* __restrict__ p1,
                                                    uint* __restrict__ p2) {
    __shared__ uint s0[SPAN_CAP], s1[SPAN_CAP], s2[SPAN_CAP];
    __shared__ int ldeg[256], lcur[256], sscan[256];
    const int t = threadIdx.x;
    const int b = blockIdx.x;
    const int nlo = b << 8;
    const int base = bbase[b];
    int span = bcnt[b];
    if (span > SPAN_CAP) span = SPAN_CAP;
    ldeg[t] = 0;
    __syncthreads();
    for (int i = t; i < span; i += 256)
        atomicAdd(&ldeg[(p0[base + i] >> 16) & 0xFFu], 1);
    __syncthreads();
    int v = ldeg[t];
    sscan[t] = v; __syncthreads();
    for (int o = 1; o < 256; o <<= 1) {
        int u = (t >= o) ? sscan[t - o] : 0;
        __syncthreads();
        sscan[t] += u;
        __syncthreads();
    }
    int exc = sscan[t] - v;
    lcur[t] = exc;
    int gi = nlo + t;
    if (gi < NN) offs[gi] = base + exc;
    else if (gi < 50176) offs[gi] = NE;
    __syncthreads();
    for (int i = t; i < span; i += 256) {
        uint r0 = p0[base + i], r1 = p1[base + i], r2 = p2[base + i];
        int pos = atomicAdd(&lcur[(r0 >> 16) & 0xFFu], 1);
        s0[pos] = r0; s1[pos] = r1; s2[pos] = r2;
    }
    __syncthreads();
    for (int i = t; i < span; i += 256) {
        p0[base + i] = s0[i]; p1[base + i] = s1[i]; p2[base + i] = s2[i];
    }
}

// ---------- Layer 1 aggregation (R12-proven) ----------
__global__ __launch_bounds__(256) void aggr1_kernel(
    const float* __restrict__ x,
    const uint* __restrict__ p0, const uint* __restrict__ p1, const uint* __restrict__ p2,
    const int* __restrict__ offs,
    const float* __restrict__ We1, const float* __restrict__ be1,
    float* __restrict__ z1)
{
    __shared__ float sWe[32];
    __shared__ float sbe[8];
    int tid = threadIdx.x;
    if (tid < 32) { int k = tid >> 3, dd = tid & 7; sWe[tid] = (dd < 7) ? We1[k * 7 + dd] : 0.f; }
    if (tid < 8)  sbe[tid] = (tid < 7) ? be1[tid] : 0.f;
    __syncthreads();

    const int w = tid >> 6, lane = tid & 63;
    const int jg = lane >> 3, d = lane & 7;

    for (int n = blockIdx.x * 4 + w; n < NN; n += gridDim.x * 4) {
        const int off = offs[n];
        const int deg = offs[n + 1] - off;
        float acc = 0.f;
        for (int j0 = 0; j0 < deg; j0 += 16) {
            int ja = j0 + jg;
            int jb = j0 + 8 + jg;
            int ia = off + ((ja < deg) ? ja : 0);
            int ib = off + ((jb < deg) ? jb : 0);
            uint r0a = p0[ia], r1a = p1[ia], r2a = p2[ia];
            uint r0b = p0[ib], r1b = p1[ib], r2b = p2[ib];
            float xa = (d < 7) ? x[(size_t)(r0a & 0xFFFFu) * 7 + d] : 0.f;
            float xb = (d < 7) ? x[(size_t)(r0b & 0xFFFFu) * 7 + d] : 0.f;
            float va = sbe[d] + bf2f_lo(r1a) * sWe[d] + bf2f_hi(r1a) * sWe[8 + d]
                     + bf2f_lo(r2a) * sWe[16 + d] + bf2f_hi(r2a) * sWe[24 + d] + xa;
            float vb = sbe[d] + bf2f_lo(r1b) * sWe[d] + bf2f_hi(r1b) * sWe[8 + d]
                     + bf2f_lo(r2b) * sWe[16 + d] + bf2f_hi(r2b) * sWe[24 + d] + xb;
            va = (d < 7 && ja < deg) ? fmaxf(va, 0.f) : 0.f;
            vb = (d < 7 && jb < deg) ? fmaxf(vb, 0.f) : 0.f;
            acc += va + vb;
        }
        acc += __shfl_xor(acc, 8);
        acc += __shfl_xor(acc, 16);
        acc += __shfl_xor(acc, 32);
        if (jg == 0)
            z1[(size_t)n * 8 + d] = (d < 7) ? (x[(size_t)n * 7 + d] + acc) : 0.f;
    }
}

// ---------- node-1 MLP via MFMA (R12-proven) ----------
__global__ __launch_bounds__(256) void node1_kernel(
    const float* __restrict__ z1,
    const float* __restrict__ W1a, const float* __restrict__ b1a,
    const float* __restrict__ W1b, const float* __restrict__ b1b,
    uint* __restrict__ h1u)
{
    __shared__ __align__(16) ushort sT[64 * MSTRIDE];
    __shared__ __align__(16) ushort sO[64 * 64];
    const int t = threadIdx.x;
    const int w = t >> 6, lane = t & 63;
    const int qm = lane & 15, quad = lane >> 4;
    const int n0 = blockIdx.x * 64;
    const int node = n0 + w * 16 + qm;

    short8 wa1n[4];
    #pragma unroll
    for (int nt = 0; nt < 4; ++nt) {
        short8 v = (short8)0;
        if (quad == 0) {
            #pragma unroll
            for (int j = 0; j < 7; ++j)
                v[j] = (short)f2bf(W1a[j * 64 + nt * 16 + qm]);
        }
        wa1n[nt] = v;
    }
    short8 wb1[2][4];
    #pragma unroll
    for (int s = 0; s < 2; ++s)
        #pragma unroll
        for (int nt = 0; nt < 4; ++nt) {
            short8 v;
            #pragma unroll
            for (int j = 0; j < 8; ++j)
                v[j] = (short)f2bf(W1b[(s * 32 + quad * 8 + j) * 64 + nt * 16 + qm]);
            wb1[s][nt] = v;
        }
    float ba[4], bb[4];
    #pragma unroll
    for (int nt = 0; nt < 4; ++nt) { ba[nt] = b1a[nt * 16 + qm]; bb[nt] = b1b[nt * 16 + qm]; }

    short8 af1 = (short8)0;
    if (quad == 0 && node < NN) {
        const float4 za = *(const float4*)(z1 + (size_t)node * 8);
        const float4 zbv = *(const float4*)(z1 + (size_t)node * 8 + 4);
        af1[0] = (short)f2bf(za.x); af1[1] = (short)f2bf(za.y);
        af1[2] = (short)f2bf(za.z); af1[3] = (short)f2bf(za.w);
        af1[4] = (short)f2bf(zbv.x); af1[5] = (short)f2bf(zbv.y);
        af1[6] = (short)f2bf(zbv.z); af1[7] = (short)f2bf(zbv.w);
    }
    float4v acc[4];
    #pragma unroll
    for (int nt = 0; nt < 4; ++nt) {
        acc[nt] = (float4v){0.f, 0.f, 0.f, 0.f};
        acc[nt] = __builtin_amdgcn_mfma_f32_16x16x32_bf16(af1, wa1n[nt], acc[nt], 0, 0, 0);
    }
    #pragma unroll
    for (int nt = 0; nt < 4; ++nt)
        #pragma unroll
        for (int r = 0; r < 4; ++r)
            sT[(w * 16 + quad * 4 + r) * MSTRIDE + nt * 16 + qm] =
                (ushort)f2bf(fmaxf(acc[nt][r] + ba[nt], 0.f));
    __syncthreads();

    #pragma unroll
    for (int nt = 0; nt < 4; ++nt) acc[nt] = (float4v){0.f, 0.f, 0.f, 0.f};
    #pragma unroll
    for (int s = 0; s < 2; ++s) {
        short8 af = *(const short8*)&sT[(w * 16 + qm) * MSTRIDE + s * 32 + quad * 8];
        #pragma unroll
        for (int nt = 0; nt < 4; ++nt)
            acc[nt] = __builtin_amdgcn_mfma_f32_16x16x32_bf16(af, wb1[s][nt], acc[nt], 0, 0, 0);
    }
    #pragma unroll
    for (int nt = 0; nt < 4; ++nt)
        #pragma unroll
        for (int r = 0; r < 4; ++r)
            sO[(w * 16 + quad * 4 + r) * 64 + nt * 16 + qm] =
                (ushort)f2bf(fmaxf(acc[nt][r] + bb[nt], 0.f));
    __syncthreads();
    for (int i = t; i < 64 * 32; i += 256) {
        int nd = i >> 5;
        if (n0 + nd < NN) h1u[(size_t)(n0 + nd) * 32 + (i & 31)] = ((const uint*)sO)[i];
    }
}

// ---------- Layer 2 aggregation: R12 structure + packed-f32 (v_pk_fma) inner math ----------
__global__ __launch_bounds__(256) void aggr2_kernel(
    const uint* __restrict__ h1u,
    const uint* __restrict__ p0, const uint* __restrict__ p1, const uint* __restrict__ p2,
    const int* __restrict__ offs,
    const float* __restrict__ We2, const float* __restrict__ be2,
    uint* __restrict__ zb)
{
    __shared__ float sWe[256];
    __shared__ float sbe[64];
    int tid = threadIdx.x;
    sWe[tid] = We2[tid];
    if (tid < 64) sbe[tid] = be2[tid];
    __syncthreads();
    const int w = tid >> 6, lane = tid & 63;
    const int l = lane & 31;
    const int half8 = (lane >> 5) << 3;
    const int n = blockIdx.x * 4 + w;
    const int off = offs[n];
    const int deg = offs[n + 1] - off;
    float2v w0v, w1v, w2v, w3v, bbv;
    w0v[0] = sWe[2 * l];       w0v[1] = sWe[2 * l + 1];
    w1v[0] = sWe[64 + 2 * l];  w1v[1] = sWe[64 + 2 * l + 1];
    w2v[0] = sWe[128 + 2 * l]; w2v[1] = sWe[128 + 2 * l + 1];
    w3v[0] = sWe[192 + 2 * l]; w3v[1] = sWe[192 + 2 * l + 1];
    bbv[0] = sbe[2 * l];       bbv[1] = sbe[2 * l + 1];
    const float2v zero2 = {0.f, 0.f};

    float2v accv = zero2;
    for (int jb = 0; jb < deg; jb += 16) {
        int m = deg - jb;
        int ll = (lane < 16) ? ((lane < m) ? lane : 0) : 0;
        int idx = off + jb + ll;
        int sx = (int)(p0[idx] & 0xFFFFu);
        uint e01 = p1[idx];
        uint e23 = p2[idx];
        uint g[8];
        #pragma unroll
        for (int k = 0; k < 8; ++k) {               // 8 independent dword gathers in flight
            int mk = k + half8;
            int sk = __shfl(sx, (mk < m) ? mk : 0);
            g[k] = h1u[(size_t)sk * 32 + l];
        }
        #pragma unroll
        for (int k = 0; k < 8; ++k) {
            int mk = k + half8;
            int sl = (mk < m) ? mk : 0;
            uint py = (uint)__shfl((int)e01, sl);
            uint pz = (uint)__shfl((int)e23, sl);
            // packed math: 4 v_pk_fma_f32 + pk add/max
            float2v bv = bbv + bf2f_lo(py) * w0v + bf2f_hi(py) * w1v
                       + bf2f_lo(pz) * w2v + bf2f_hi(pz) * w3v;
            float2v gv;
            gv[0] = bf2f_lo(g[k]);
            gv[1] = bf2f_hi(g[k]);
            float2v tv = gv + bv;
            tv[0] = fmaxf(tv[0], 0.f);
            tv[1] = fmaxf(tv[1], 0.f);
            if (mk < m) accv += tv;
        }
    }
    float accx = accv[0], accy = accv[1];
    accx += __shfl_xor(accx, 32);
    accy += __shfl_xor(accy, 32);
    if (lane < 32) {
        uint sw = h1u[(size_t)n * 32 + l];
        float zx = bf2f_lo(sw) + accx;
        float zy = bf2f_hi(sw) + accy;
        zb[(size_t)n * 32 + l] = f2bf(zx) | (f2bf(zy) << 16);
    }
}

// ---------- Layer 2 MLP via MFMA + segmented-reduction pooling (R12-proven) ----------
__global__ __launch_bounds__(256) void mlp2_kernel(
    const uint* __restrict__ zb,
    const float* __restrict__ W2a, const float* __restrict__ b2a,
    const float* __restrict__ W2b, const float* __restrict__ b2b,
    const int* __restrict__ batch,
    float* __restrict__ sums, float* __restrict__ cnt)
{
    __shared__ __align__(16) ushort sT[64 * MSTRIDE];
    __shared__ float sH[64 * 64];
    __shared__ int sB[64];
    __shared__ float pbuf[4][64];
    __shared__ int pcnt[4];
    const int t = threadIdx.x;
    const int w = t >> 6, lane = t & 63;
    const int qm = lane & 15, quad = lane >> 4;
    const int n0 = blockIdx.x * 64;
    const int node = n0 + w * 16 + qm;
    const int nv = (NN - n0 < 64) ? (NN - n0) : 64;

    if (t < 64) sB[t] = (n0 + t < NN) ? batch[n0 + t] : -2;

    short8 wa[2][4], wb[2][4];
    #pragma unroll
    for (int s = 0; s < 2; ++s)
        #pragma unroll
        for (int nt = 0; nt < 4; ++nt) {
            short8 va, vb;
            #pragma unroll
            for (int j = 0; j < 8; ++j) {
                int k = s * 32 + quad * 8 + j, n = nt * 16 + qm;
                va[j] = (short)f2bf(W2a[k * 64 + n]);
                vb[j] = (short)f2bf(W2b[k * 64 + n]);
            }
            wa[s][nt] = va; wb[s][nt] = vb;
        }
    float ba[4], bb[4];
    #pragma unroll
    for (int nt = 0; nt < 4; ++nt) { ba[nt] = b2a[nt * 16 + qm]; bb[nt] = b2b[nt * 16 + qm]; }

    float4v acc[4];
    #pragma unroll
    for (int nt = 0; nt < 4; ++nt) acc[nt] = (float4v){0.f, 0.f, 0.f, 0.f};
    #pragma unroll
    for (int s = 0; s < 2; ++s) {
        uint4 zw = (node < NN) ? *(const uint4*)&zb[(size_t)node * 32 + s * 16 + quad * 4]
                               : make_uint4(0, 0, 0, 0);
        short8 af;
        *(uint4*)&af = zw;
        #pragma unroll
        for (int nt = 0; nt < 4; ++nt)
            acc[nt] = __builtin_amdgcn_mfma_f32_16x16x32_bf16(af, wa[s][nt], acc[nt], 0, 0, 0);
    }
    #pragma unroll
    for (int nt = 0; nt < 4; ++nt)
        #pragma unroll
        for (int r = 0; r < 4; ++r)
            sT[(w * 16 + quad * 4 + r) * MSTRIDE + nt * 16 + qm] =
                (ushort)f2bf(fmaxf(acc[nt][r] + ba[nt], 0.f));
    __syncthreads();

    #pragma unroll
    for (int nt = 0; nt < 4; ++nt) acc[nt] = (float4v){0.f, 0.f, 0.f, 0.f};
    #pragma unroll
    for (int s = 0; s < 2; ++s) {
        short8 af = *(const short8*)&sT[(w * 16 + qm) * MSTRIDE + s * 32 + quad * 8];
        #pragma unroll
        for (int nt = 0; nt < 4; ++nt)
            acc[nt] = __builtin_amdgcn_mfma_f32_16x16x32_bf16(af, wb[s][nt], acc[nt], 0, 0, 0);
    }
    #pragma unroll
    for (int nt = 0; nt < 4; ++nt)
        #pragma unroll
        for (int r = 0; r < 4; ++r)
            sH[(w * 16 + quad * 4 + r) * 64 + nt * 16 + qm] = fmaxf(acc[nt][r] + bb[nt], 0.f);
    __syncthreads();

    const int glo = sB[0];
    const int ghi = sB[nv - 1];
    const int c = t >> 6, d = t & 63;
    for (int g = glo; g <= ghi; ++g) {
        float p = 0.f;
        int lc = 0;
        #pragma unroll 4
        for (int i = 0; i < 16; ++i) {
            int nd = c * 16 + i;
            if (sB[nd] == g) { p += sH[nd * 64 + d]; ++lc; }
        }
        pbuf[c][d] = p;
        if (d == 0) pcnt[c] = lc;
        __syncthreads();
        int tc = pcnt[0] + pcnt[1] + pcnt[2] + pcnt[3];
        if (tc > 0) {
            if (c == 0) {
                float tot = pbuf[0][d] + pbuf[1][d] + pbuf[2][d] + pbuf[3][d];
                atomicAdd(&sums[(size_t)g * 64 + d], tot);
            }
            if (t == 0) atomicAdd(&cnt[g], (float)tc);
        }
        __syncthreads();
    }
}

// ---------- FC ----------
__global__ __launch_bounds__(256) void fc_kernel(
    const float* __restrict__ sums, const float* __restrict__ cnt,
    const float* __restrict__ Wfc, const float* __restrict__ bfc,
    float* __restrict__ out)
{
    int gid = blockIdx.x * blockDim.x + threadIdx.x;
    if (gid >= NG * 12) return;
    int g = gid / 12, jj = gid - g * 12;
    float inv = 1.f / fmaxf(cnt[g], 1.f);
    float acc = bfc[jj];
    #pragma unroll 8
    for (int k = 0; k < 64; ++k) acc += sums[(size_t)g * 64 + k] * inv * Wfc[k * 12 + jj];
    out[gid] = acc;
}

extern "C" void kernel_launch(void* const* d_in, const int* in_sizes, int n_in,
                              void* d_out, int out_size, void* d_ws, size_t ws_size,
                              hipStream_t stream)
{
    (void)in_sizes; (void)n_in; (void)out_size; (void)ws_size;
    const float*  x    = (const float*)d_in[0];
    const float4* ea   = (const float4*)d_in[1];
    const int*    eidx = (const int*)d_in[2];
    const int*    batch= (const int*)d_in[3];
    const float*  We1  = (const float*)d_in[4];
    const float*  be1  = (const float*)d_in[5];
    const float*  W1a  = (const float*)d_in[6];
    const float*  b1a  = (const float*)d_in[7];
    const float*  W1b  = (const float*)d_in[8];
    const float*  b1b  = (const float*)d_in[9];
    const float*  We2  = (const float*)d_in[10];
    const float*  be2  = (const float*)d_in[11];
    const float*  W2a  = (const float*)d_in[12];
    const float*  b2a  = (const float*)d_in[13];
    const float*  W2b  = (const float*)d_in[14];
    const float*  b2b  = (const float*)d_in[15];
    const float*  Wfc  = (const float*)d_in[16];
    const float*  bfc  = (const float*)d_in[17];
    float* out = (float*)d_out;
    float* ws  = (float*)d_ws;

    int*   bcnt  = (int*)(ws + OFF_BCNT);
    float* sums  = ws + OFF_SUMS;
    float* cnt   = ws + OFF_CNT;
    int*   bbase = (int*)(ws + OFF_BBASE);
    int*   bcur  = (int*)(ws + OFF_BCUR);
    int*   offs  = (int*)(ws + OFF_OFFS);
    uint*  p0    = (uint*)(ws + OFF_P0);
    uint*  p1    = (uint*)(ws + OFF_P1);
    uint*  p2    = (uint*)(ws + OFF_P2);
    float* z1    = ws + OFF_Z1;
    uint*  h1u   = (uint*)(ws + OFF_H1);
    uint*  zb    = (uint*)(ws + OFF_Z);

    hipMemsetAsync(d_ws, 0, (size_t)ZERO_UNITS * 4, stream);

    bhist_kernel<<<256, 256, 0, stream>>>(eidx, bcnt);
    bscan_kernel<<<1, 256, 0, stream>>>(bcnt, bbase, bcur);
    bin_kernel  <<<NTILE, 256, 0, stream>>>(eidx, ea, bcur, p0, p1, p2);
    build_kernel<<<NB2, 256, 0, stream>>>(bbase, bcnt, offs, p0, p1, p2);
    aggr1_kernel<<<2500, 256, 0, stream>>>(x, p0, p1, p2, offs, We1, be1, z1);
    node1_kernel<<<(NN + 63) / 64, 256, 0, stream>>>(z1, W1a, b1a, W1b, b1b, h1u);
    aggr2_kernel<<<12500, 256, 0, stream>>>(h1u, p0, p1, p2, offs, We2, be2, zb);
    mlp2_kernel <<<(NN + 63) / 64, 256, 0, stream>>>(zb, W2a, b2a, W2b, b2b, batch, sums, cnt);
    fc_kernel   <<<(NG * 12 + 255) / 256, 256, 0, stream>>>(sums, cnt, Wfc, bfc, out);
}